// Round 13
// baseline (5181.311 us; speedup 1.0000x reference)
//
#include <hip/hip_runtime.h>

// ---------------------------------------------------------------------------
// multiStepModel: LSTM encoder (T=365) -> relu -> constant-input LSTM decoder
// (90 steps) -> relu -> FC.  Persistent cooperative kernel, 1 WG/CU.
// R13 = R12 + SELF-VALIDATING h exchange: each stored h word carries a step-
// epoch bit in its lo-f16 LSB (error ~2^-21, negligible).  Consumers poll by
// loading the data itself until all 64 parity bits match the expected epoch
// -> the flag LLC round-trip and 2 of 3 per-step syncthreads disappear.
// 3-buffer rotation makes overwrite WAR-safe (skew self-bounded by the data
// dependency).  LDS B-tile double-buffered (fits via R12's W-in-registers).
// One legacy flag barrier remains at the encoder->decoder transition only.
// ---------------------------------------------------------------------------

namespace {
constexpr int B = 128, T = 365, IN = 64, COV = 256, H = 512, OUTL = 90;
constexpr int GB = 4;            // batch groups (independent quorums)
constexpr int GJ = 64;           // hidden groups
constexpr int NWG = GB * GJ;     // 256 workgroups, 1/CU
constexpr int NT = 256;          // threads per WG (4 waves)
constexpr int BS = B / GB;       // 32 batch rows per WG
constexpr int HU = H / GJ;       // 8 hidden units per WG
constexpr int NR = 4 * HU;       // 32 gate rows per WG (reordered unit*4+gate)
constexpr int NSLOT_H = 64;      // 512/8 16B slots (h part of K)
constexpr int NSLOT = 72;        // + 64/8 slots (x part)
}

using ull = unsigned long long;
typedef __attribute__((ext_vector_type(8))) short short8;
typedef __attribute__((ext_vector_type(8))) _Float16 half8;
typedef __attribute__((ext_vector_type(4))) float f32x4;

__device__ unsigned int g_h[3][B][H];          // packed f16 (hi|lo,tagged) state
__device__ float g_part[OUTL][GJ][B];          // per-hidden-group FC partials
__device__ __align__(256) int g_flag[GB][64];  // transition barrier only

__device__ __forceinline__ float sigfast(float x) {
  return __builtin_amdgcn_rcpf(1.0f + __expf(-x));
}
__device__ __forceinline__ float tanhfast(float x) {
  return 1.0f - 2.0f * __builtin_amdgcn_rcpf(__expf(2.0f * x) + 1.0f);
}

__device__ __forceinline__ float4 fma4(float4 a, float4 b, float4 c) {
  c.x = fmaf(a.x, b.x, c.x); c.y = fmaf(a.y, b.y, c.y);
  c.z = fmaf(a.z, b.z, c.z); c.w = fmaf(a.w, b.w, c.w);
  return c;
}
__device__ __forceinline__ float hsum4(float4 a) { return (a.x + a.y) + (a.z + a.w); }

__device__ __forceinline__ unsigned int pack_split(float v) {
  _Float16 hi = (_Float16)v;
  _Float16 lo = (_Float16)(v - (float)hi);
  return ((unsigned int)__builtin_bit_cast(unsigned short, hi) << 16) |
         (unsigned int)__builtin_bit_cast(unsigned short, lo);
}
__device__ __forceinline__ float unpack_split(unsigned int u) {
  _Float16 hi = __builtin_bit_cast(_Float16, (unsigned short)(u >> 16));
  _Float16 lo = __builtin_bit_cast(_Float16, (unsigned short)(u & 0xFFFFu));
  return (float)hi + (float)lo;
}

// 8 consecutive fp32 -> f16 hi/lo fragment pair
__device__ __forceinline__ void cvt8(const float* src, half8& hi, half8& lo) {
  float4 p0 = ((const float4*)src)[0], p1 = ((const float4*)src)[1];
  float f[8] = {p0.x, p0.y, p0.z, p0.w, p1.x, p1.y, p1.z, p1.w};
#pragma unroll
  for (int j = 0; j < 8; ++j) {
    _Float16 h_ = (_Float16)f[j];
    hi[j] = h_;
    lo[j] = (_Float16)(f[j] - (float)h_);
  }
}

// k_init: deterministic epoch-parity reset each launch (graph-replay safe).
// First reads: buf1@s=1 expects e=0, buf2@s=2 expects e=0, buf0@s=3 expects
// e=1 -> init LSBs to the complement: buf0=0, buf1=1, buf2=1.
__global__ void __launch_bounds__(256) k_init() {
  const int id = blockIdx.x * 256 + threadIdx.x;
  unsigned* h0 = &g_h[0][0][0];
  if (id < B * H) {
    h0[id] = 0u;
    h0[B * H + id] = 1u;
    h0[2 * B * H + id] = 1u;
  }
  if (blockIdx.x == 0 && threadIdx.x < GB * 64)
    g_flag[threadIdx.x >> 6][threadIdx.x & 63] = 0;
}

__global__ void __launch_bounds__(NT, 1) k_lstm(
    const float* __restrict__ input, const float* __restrict__ covar,
    const float* __restrict__ W_ih1, const float* __restrict__ W_hh1,
    const float* __restrict__ b1,    const float* __restrict__ W_ih2,
    const float* __restrict__ W_hh2, const float* __restrict__ b2,
    const float* __restrict__ W_fc) {
  // Double-buffered B tiles (W is register-resident).  Slot s of row r at
  // s ^ (r&7).  2 x 73.7 KB + pb + aux ~= 152 KB LDS (1 WG/CU by design).
  __shared__ __align__(16) short bH[2][BS][NSLOT * 8];
  __shared__ __align__(16) short bL[2][BS][NSLOT * 8];
  __shared__ float pb_lds[NR][33];                    // covproj+b1 / proj2
  __shared__ float aux[4][16];                        // decoder FC combine

  const int tid = threadIdx.x;
  const int gb  = blockIdx.x & (GB - 1);
  const int gj  = blockIdx.x >> 2;
  const int bg0 = gb * BS;
  const int j0  = gj * HU;

  const int lane  = tid & 63;
  const int wv    = tid >> 6;
  const int rows0 = (wv >> 1) * 16;        // gate-row tile
  const int cols0 = (wv & 1) * 16;         // batch tile
  const int ra    = rows0 + (lane & 15);   // A row (reordered gate row)
  const int b_l   = cols0 + (lane & 15);   // B row == D col == batch
  const int cc    = lane >> 4;             // k-chunk / gate-quad 0..3
  const int x7    = lane & 7;              // XOR swizzle key (== b_l&7)
  const int u_l   = (wv >> 1) * 4 + cc;    // this lane's unit 0..7

  const int bl = tid >> 3;                 // staging row 0..31
  const int sg = tid & 7;                  // staging phase 0..7
  const int bt = tid & 15;                 // fp32 helper mapping
  const int rt = tid >> 4;

  const int growA = (ra & 3) * H + j0 + (ra >> 2);   // lane's global W row

  // ---- loop-invariant W fragments in registers (R12-proven) ----
  half8 wA[16], wLo[16];     // h-part (K blocks 0..15)
  half8 xA[2],  xLo[2];      // x-part (encoder only)

  auto stage_whh_regs = [&](const float* Whh) {
    const float* base = Whh + (size_t)growA * H + cc * 8;
#pragma unroll
    for (int kb = 0; kb < 16; ++kb) cvt8(base + kb * 32, wA[kb], wLo[kb]);
  };

  // x staging into B slots 64..71 of tile tp
  auto load_x_regs = [&](int tn, float4& p0, float4& p1) {
    const float* src = input + ((size_t)(bg0 + bl) * T + tn) * IN + sg * 8;
    p0 = ((const float4*)src)[0];
    p1 = ((const float4*)src)[1];
  };
  auto stage_x_regs = [&](int tp, float4 p0, float4 p1) {
    float f[8] = {p0.x, p0.y, p0.z, p0.w, p1.x, p1.y, p1.z, p1.w};
    short8 hi, lo;
#pragma unroll
    for (int j = 0; j < 8; ++j) {
      _Float16 h_ = (_Float16)f[j];
      hi[j] = __builtin_bit_cast(short, h_);
      lo[j] = __builtin_bit_cast(short, (_Float16)(f[j] - (float)h_));
    }
    const int s2 = (NSLOT_H + sg) ^ (bl & 7);
    *(short8*)&bH[tp][bl][s2 * 8] = hi;
    *(short8*)&bL[tp][bl][s2 * 8] = lo;
  };

  // ---- self-validating h poll: load until all parity bits == e ----
  auto poll_h = [&](int rb, unsigned e, ull (&tmp)[32]) {
    const ull* hr = (const ull*)&g_h[rb][bg0 + bl][0];   // 256 ull per row
    for (;;) {
      unsigned miss = 0;
#pragma unroll
      for (int i = 0; i < 32; ++i) {
        tmp[i] = __hip_atomic_load(hr + sg + 8 * i, __ATOMIC_RELAXED,
                                   __HIP_MEMORY_SCOPE_AGENT);
        miss |= ((unsigned)tmp[i] ^ e) | ((unsigned)(tmp[i] >> 32) ^ e);
      }
      if (!__any((int)(miss & 1u))) break;
      __builtin_amdgcn_s_sleep(1);
    }
  };
  auto commit_h = [&](int tp, ull (&tmp)[32]) {
#pragma unroll
    for (int i = 0; i < 32; ++i) {
      const int m = sg + 8 * i;                  // ull index 0..255
      const int s2 = (m >> 2) ^ (bl & 7);        // swizzled 16B slot
      const int p = m & 3;                       // word within slot
      const unsigned u0 = (unsigned)tmp[i], u1 = (unsigned)(tmp[i] >> 32);
      ((unsigned*)&bH[tp][bl][s2 * 8])[p] = (u0 >> 16) | (u1 & 0xFFFF0000u);
      ((unsigned*)&bL[tp][bl][s2 * 8])[p] = (u0 & 0xFFFFu) | (u1 << 16);
    }
  };

  // tagged h' store: lo-LSB = epoch bit (error ~2^-21 relative, negligible)
  auto store_h = [&](int wb, unsigned we, float hv) {
    const unsigned u = (pack_split(hv) & ~1u) | we;
    __hip_atomic_store(&g_h[wb][bg0 + b_l][j0 + u_l], u,
                       __ATOMIC_RELAXED, __HIP_MEMORY_SCOPE_AGENT);
  };

  // One MFMA k-block; A from registers, B from LDS tile tp.
  auto mfma_kb = [&](int tp, int kb, half8 ah, half8 al,
                     f32x4& aA, f32x4& aB, f32x4& aC) {
    const int s2 = (kb * 4 + cc) ^ x7;
    const half8 bh = __builtin_bit_cast(half8, *(const short8*)&bH[tp][b_l][s2 * 8]);
    const half8 bo = __builtin_bit_cast(half8, *(const short8*)&bL[tp][b_l][s2 * 8]);
    aA = __builtin_amdgcn_mfma_f32_16x16x32_f16(ah, bh, aA, 0, 0, 0);
    aB = __builtin_amdgcn_mfma_f32_16x16x32_f16(ah, bo, aB, 0, 0, 0);
    aC = __builtin_amdgcn_mfma_f32_16x16x32_f16(al, bh, aC, 0, 0, 0);
  };

  // legacy flag barrier — used once at the encoder->decoder transition
  auto gbar = [&](int nb) {
    __syncthreads();
    if (tid == 0)
      __hip_atomic_store(&g_flag[gb][gj], nb, __ATOMIC_RELAXED,
                         __HIP_MEMORY_SCOPE_AGENT);
    if (tid < 64) {
      while (__hip_atomic_load(&g_flag[gb][tid], __ATOMIC_RELAXED,
                               __HIP_MEMORY_SCOPE_AGENT) < nb)
        __builtin_amdgcn_s_sleep(1);
    }
    __syncthreads();
  };

  // ======================= one-time setup =======================
  stage_whh_regs(W_hh1);
  {  // x-part W fragments (first IN=64 cols of W_ih1)
    const float* base = W_ih1 + (size_t)growA * (IN + COV) + cc * 8;
#pragma unroll
    for (int xk = 0; xk < 2; ++xk) cvt8(base + xk * 32, xA[xk], xLo[xk]);
  }
  {  // covariate projection + b1 -> pb_lds (fp32, once)
    auto wrow = [&](int r) { return (r & 3) * H + j0 + (r >> 2); };
    const int r0 = rt, r1 = rt + 16;
    const int row0 = wrow(r0), row1 = wrow(r1);
    const float4* c0 = (const float4*)(covar + (size_t)(bg0 + bt) * COV);
    const float4* c1 = (const float4*)(covar + (size_t)(bg0 + bt + 16) * COV);
    const float4* w0 = (const float4*)(W_ih1 + (size_t)row0 * (IN + COV) + IN);
    const float4* w1 = (const float4*)(W_ih1 + (size_t)row1 * (IN + COV) + IN);
    float4 a00 = {0, 0, 0, 0}, a01 = a00, a10 = a00, a11 = a00;
    for (int k = 0; k < COV / 4; ++k) {
      float4 va = c0[k], vb = c1[k], wa = w0[k], wb = w1[k];
      a00 = fma4(va, wa, a00); a01 = fma4(va, wb, a01);
      a10 = fma4(vb, wa, a10); a11 = fma4(vb, wb, a11);
    }
    pb_lds[r0][bt]      = hsum4(a00) + b1[row0];
    pb_lds[r1][bt]      = hsum4(a01) + b1[row1];
    pb_lds[r0][bt + 16] = hsum4(a10) + b1[row0];
    pb_lds[r1][bt + 16] = hsum4(a11) + b1[row1];
  }
  {  // stage x_0 into tile 0
    float4 p0, p1;
    load_x_regs(0, p0, p1);
    stage_x_regs(0, p0, p1);
  }
  __syncthreads();   // pb_lds + x_0 ready

  float pb4[4];
#pragma unroll
  for (int q = 0; q < 4; ++q) pb4[q] = pb_lds[rows0 + cc * 4 + q][b_l];

  float c_state = 0.0f;

  auto cellp = [&](const f32x4& acc) -> float {
    const float gi = acc[0] + pb4[0];
    const float gf = acc[1] + pb4[1];
    const float gg = acc[2] + pb4[2];
    const float go = acc[3] + pb4[3];
    c_state = sigfast(gf) * c_state + sigfast(gi) * tanhfast(gg);
    return sigfast(go) * tanhfast(c_state);
  };

  // =================== encoder: 365 steps (step sc = t) ===================
  for (int t = 0; t < T; ++t) {
    const int tp = t & 1;
    if (t > 0) {
      ull tmp[32];
      poll_h(t % 3, (unsigned)((t / 3) & 1), tmp);   // poll == data load
      commit_h(tp, tmp);
    }
    __syncthreads();                       // the ONLY per-step barrier
    float4 xp0, xp1;
    const bool havex = (t + 1 < T);
    if (havex) load_x_regs(t + 1, xp0, xp1);         // flies under MFMA
    f32x4 aA = {0.f, 0.f, 0.f, 0.f}, aB = aA, aC = aA;
#pragma unroll
    for (int xk = 0; xk < 2; ++xk)
      mfma_kb(tp, 16 + xk, xA[xk], xLo[xk], aA, aB, aC);
    if (t > 0) {
#pragma unroll
      for (int kb = 0; kb < 16; ++kb)
        mfma_kb(tp, kb, wA[kb], wLo[kb], aA, aB, aC);
    }
    f32x4 acc;
#pragma unroll
    for (int q = 0; q < 4; ++q) acc[q] = aA[q] + aB[q] + aC[q];
    float hv = cellp(acc);
    if (t == T - 1) hv = fmaxf(hv, 0.0f);            // relu(h_enc)
    store_h((t + 1) % 3, (unsigned)(((t + 1) / 3) & 1), hv);
    if (havex) stage_x_regs((t + 1) & 1, xp0, xp1);  // safe: all waves past
  }                                                  // this step's barrier

  // ====== transition (flag barrier once): proj2 = [h_enc,covar]@W_ih2^T+b2 ==
  gbar(1);                       // all h_enc stores visible
  {
    auto wrow = [&](int r) { return (r & 3) * H + j0 + (r >> 2); };
    const int b0 = bt, b1v = bt + 16;
    const int r0 = rt, r1 = rt + 16;
    const int row0 = wrow(r0), row1 = wrow(r1);
    const float* w0 = W_ih2 + (size_t)row0 * (H + COV);
    const float* w1 = W_ih2 + (size_t)row1 * (H + COV);
    const ull* h0 = (const ull*)&g_h[T % 3][bg0 + b0][0];
    const ull* h1 = (const ull*)&g_h[T % 3][bg0 + b1v][0];
    float a00 = 0.f, a01 = 0.f, a10 = 0.f, a11 = 0.f;
    for (int m = 0; m < H / 2; ++m) {   // h part from tagged LLC state
      const ull v0 = __hip_atomic_load(h0 + m, __ATOMIC_RELAXED,
                                       __HIP_MEMORY_SCOPE_AGENT);
      const ull v1 = __hip_atomic_load(h1 + m, __ATOMIC_RELAXED,
                                       __HIP_MEMORY_SCOPE_AGENT);
      const float h00 = unpack_split((unsigned)v0);
      const float h01 = unpack_split((unsigned)(v0 >> 32));
      const float h10 = unpack_split((unsigned)v1);
      const float h11 = unpack_split((unsigned)(v1 >> 32));
      const float wa0 = w0[2 * m], wa1 = w0[2 * m + 1];
      const float wb0 = w1[2 * m], wb1 = w1[2 * m + 1];
      a00 += h00 * wa0 + h01 * wa1;  a01 += h00 * wb0 + h01 * wb1;
      a10 += h10 * wa0 + h11 * wa1;  a11 += h10 * wb0 + h11 * wb1;
    }
    {  // covar part (fp32, cache-hot)
      const float4* c0 = (const float4*)(covar + (size_t)(bg0 + b0) * COV);
      const float4* c1 = (const float4*)(covar + (size_t)(bg0 + b1v) * COV);
      const float4* W0 = (const float4*)w0;
      const float4* W1 = (const float4*)w1;
      float4 s00 = {0, 0, 0, 0}, s01 = s00, s10 = s00, s11 = s00;
      for (int k = 0; k < COV / 4; ++k) {
        float4 ha = c0[k], hb = c1[k], wa = W0[H / 4 + k], wb = W1[H / 4 + k];
        s00 = fma4(ha, wa, s00); s01 = fma4(ha, wb, s01);
        s10 = fma4(hb, wa, s10); s11 = fma4(hb, wb, s11);
      }
      a00 += hsum4(s00); a01 += hsum4(s01);
      a10 += hsum4(s10); a11 += hsum4(s11);
    }
    pb_lds[r0][b0]  = a00 + b2[row0];
    pb_lds[r1][b0]  = a01 + b2[row1];
    pb_lds[r0][b1v] = a10 + b2[row0];
    pb_lds[r1][b1v] = a11 + b2[row1];
  }
  stage_whh_regs(W_hh2);        // decoder recurrent W -> registers
  c_state = 0.0f;
  __syncthreads();              // pb_lds rewrite complete
#pragma unroll
  for (int q = 0; q < 4; ++q) pb4[q] = pb_lds[rows0 + cc * 4 + q][b_l];
  const float wfc = W_fc[j0 + u_l];

  // ======= decoder: 90 steps (step sc = T + ot; ot=0 reads nothing) =======
  for (int ot = 0; ot < OUTL; ++ot) {
    const int sc = T + ot;
    const int tp = ot & 1;
    if (ot > 0) {
      ull tmp[32];
      poll_h(sc % 3, (unsigned)((sc / 3) & 1), tmp);
      commit_h(tp, tmp);
    }
    __syncthreads();                       // sync1: commits visible
    f32x4 aA = {0.f, 0.f, 0.f, 0.f}, aB = aA, aC = aA;
    if (ot > 0) {
#pragma unroll
      for (int kb = 0; kb < 16; ++kb)
        mfma_kb(tp, kb, wA[kb], wLo[kb], aA, aB, aC);
    }
    f32x4 acc;
#pragma unroll
    for (int q = 0; q < 4; ++q) acc[q] = aA[q] + aB[q] + aC[q];
    const float hv = cellp(acc);           // ot==0: gates = proj2 only
    store_h((sc + 1) % 3, (unsigned)(((sc + 1) / 3) & 1), hv);
    // FC partial: relu(hv)*wfc summed over this WG's 8 units per batch row
    float fcv = fmaxf(hv, 0.0f) * wfc;
    fcv += __shfl_xor(fcv, 16);
    fcv += __shfl_xor(fcv, 32);            // sum over the 4 unit-lanes
    if (lane < 16) aux[wv][lane] = fcv;
    __syncthreads();                       // sync2: aux ready
    if (tid < 32)
      g_part[ot][gj][bg0 + tid] =
          aux[tid >> 4][tid & 15] + aux[(tid >> 4) + 2][tid & 15];
  }
}

__global__ void __launch_bounds__(256) k_reduce(const float* __restrict__ b_fc,
                                                float* __restrict__ out) {
  int id = blockIdx.x * 256 + threadIdx.x;
  if (id >= B * OUTL) return;
  int b = id / OUTL, ot = id - b * OUTL;
  float s = b_fc[0];
#pragma unroll 8
  for (int g = 0; g < GJ; ++g) s += g_part[ot][g][b];
  out[id] = s;   // out[b][ot], row-major == id
}

extern "C" void kernel_launch(void* const* d_in, const int* in_sizes, int n_in,
                              void* d_out, int out_size, void* d_ws, size_t ws_size,
                              hipStream_t stream) {
  (void)in_sizes; (void)n_in; (void)d_ws; (void)ws_size; (void)out_size;
  const float* input = (const float*)d_in[0];
  const float* covar = (const float*)d_in[1];
  const float* W_ih1 = (const float*)d_in[2];
  const float* W_hh1 = (const float*)d_in[3];
  const float* b1    = (const float*)d_in[4];
  const float* W_ih2 = (const float*)d_in[5];
  const float* W_hh2 = (const float*)d_in[6];
  const float* b2    = (const float*)d_in[7];
  const float* W_fc  = (const float*)d_in[8];
  const float* b_fc  = (const float*)d_in[9];

  k_init<<<dim3((B * H + 255) / 256), dim3(256), 0, stream>>>();
  k_lstm<<<dim3(NWG), dim3(NT), 0, stream>>>(input, covar, W_ih1, W_hh1, b1,
                                             W_ih2, W_hh2, b2, W_fc);
  k_reduce<<<dim3((B * OUTL + 255) / 256), dim3(256), 0, stream>>>(
      b_fc, (float*)d_out);
}

// Round 14
// 1395.477 us; speedup vs baseline: 3.7129x; 3.7129x over previous
//
#include <hip/hip_runtime.h>

// ---------------------------------------------------------------------------
// multiStepModel: LSTM encoder (T=365) -> relu -> constant-input LSTM decoder
// (90 steps) -> relu -> FC.  Persistent cooperative kernel, 1 WG/CU.
// R14 = R12 skeleton (best; flags + 2-buffer h, dense-coalesced LLC staging,
// W-in-registers, split-f16 3-term MFMA, register cell, fast transcendentals)
// with the decomposition rebalanced to GB=8 x GJ=32 (16 batch x 16 units per
// WG): h read-amplification and per-step LLC traffic HALVED (16->8 MB/step),
// per-thread h load/commit halved (16 ull), barrier quorum halved (32 WGs).
// ---------------------------------------------------------------------------

namespace {
constexpr int B = 128, T = 365, IN = 64, COV = 256, H = 512, OUTL = 90;
constexpr int GB = 8;            // batch groups (independent quorums)
constexpr int GJ = 32;           // hidden groups
constexpr int NWG = GB * GJ;     // 256 workgroups, 1/CU
constexpr int NT = 256;          // threads per WG (4 waves)
constexpr int BS = B / GB;       // 16 batch rows per WG
constexpr int HU = H / GJ;       // 16 hidden units per WG
constexpr int NR = 4 * HU;       // 64 gate rows per WG (row = unit*4 + gate)
constexpr int NSLOT_H = 64;      // 512/8 16B slots (h part of K)
constexpr int NSLOT = 72;        // + 64/8 slots (x part)
}

using ull = unsigned long long;
typedef __attribute__((ext_vector_type(8))) short short8;
typedef __attribute__((ext_vector_type(4))) short short4v;
typedef __attribute__((ext_vector_type(8))) _Float16 half8;
typedef __attribute__((ext_vector_type(4))) float f32x4;

__device__ unsigned int g_h[2][B][H];          // packed f16 (hi<<16|lo) state
__device__ float g_part[OUTL][GJ][B];          // per-hidden-group FC partials
__device__ __align__(256) int g_flag[GB][32];  // per-WG monotonic flags

__device__ __forceinline__ float sigfast(float x) {
  return __builtin_amdgcn_rcpf(1.0f + __expf(-x));
}
__device__ __forceinline__ float tanhfast(float x) {
  return 1.0f - 2.0f * __builtin_amdgcn_rcpf(__expf(2.0f * x) + 1.0f);
}

__device__ __forceinline__ float4 fma4(float4 a, float4 b, float4 c) {
  c.x = fmaf(a.x, b.x, c.x); c.y = fmaf(a.y, b.y, c.y);
  c.z = fmaf(a.z, b.z, c.z); c.w = fmaf(a.w, b.w, c.w);
  return c;
}
__device__ __forceinline__ float hsum4(float4 a) { return (a.x + a.y) + (a.z + a.w); }

__device__ __forceinline__ unsigned int pack_split(float v) {
  _Float16 hi = (_Float16)v;
  _Float16 lo = (_Float16)(v - (float)hi);
  return ((unsigned int)__builtin_bit_cast(unsigned short, hi) << 16) |
         (unsigned int)__builtin_bit_cast(unsigned short, lo);
}
__device__ __forceinline__ float unpack_split(unsigned int u) {
  _Float16 hi = __builtin_bit_cast(_Float16, (unsigned short)(u >> 16));
  _Float16 lo = __builtin_bit_cast(_Float16, (unsigned short)(u & 0xFFFFu));
  return (float)hi + (float)lo;
}

// 8 consecutive fp32 -> f16 hi/lo fragment pair
__device__ __forceinline__ void cvt8(const float* src, half8& hi, half8& lo) {
  float4 p0 = ((const float4*)src)[0], p1 = ((const float4*)src)[1];
  float f[8] = {p0.x, p0.y, p0.z, p0.w, p1.x, p1.y, p1.z, p1.w};
#pragma unroll
  for (int j = 0; j < 8; ++j) {
    _Float16 h_ = (_Float16)f[j];
    hi[j] = h_;
    lo[j] = (_Float16)(f[j] - (float)h_);
  }
}

__global__ void __launch_bounds__(256) k_init() {
  int t = threadIdx.x;
  if (t < GB * 32) g_flag[t >> 5][t & 31] = 0;
}

__global__ void __launch_bounds__(NT, 1) k_lstm(
    const float* __restrict__ input, const float* __restrict__ covar,
    const float* __restrict__ W_ih1, const float* __restrict__ W_hh1,
    const float* __restrict__ b1,    const float* __restrict__ W_ih2,
    const float* __restrict__ W_hh2, const float* __restrict__ b2,
    const float* __restrict__ W_fc) {
  // B operand tiles (W register-resident).  Slot s of row r at s ^ (r&7).
  __shared__ __align__(16) short bH[BS][NSLOT * 8];   // [h;x] hi  18.4 KB
  __shared__ __align__(16) short bL[BS][NSLOT * 8];   // [h;x] lo  18.4 KB
  __shared__ float pb_lds[NR][17];                    // covproj+b1 / proj2
  __shared__ float aux[4][16];                        // decoder FC combine

  const int tid = threadIdx.x;
  const int gb  = blockIdx.x & (GB - 1);       // 0..7
  const int gj  = blockIdx.x >> 3;             // 0..31
  const int bg0 = gb * BS;
  const int j0  = gj * HU;

  const int lane  = tid & 63;
  const int wv    = tid >> 6;
  const int rows0 = wv * 16;               // gate-row tile (units wv*4..+3)
  const int ra    = rows0 + (lane & 15);   // A row (reordered gate row)
  const int b_l   = lane & 15;             // B row == D col == batch (shared)
  const int cc    = lane >> 4;             // k-chunk / gate-quad 0..3
  const int x7    = lane & 7;              // XOR swizzle key (== b_l&7)
  const int u_l   = wv * 4 + cc;           // this lane's unit 0..15

  const int bl  = tid >> 4;                // staging row 0..15
  const int sg  = tid & 15;                // staging phase 0..15
  const int bt  = tid & 15;                // fp32 helper: batch 0..15
  const int rt  = tid >> 4;                // fp32 helper: row base 0..15

  const int growA = (ra & 3) * H + j0 + (ra >> 2);   // lane's global W row

  // ---- loop-invariant W fragments in registers (R12-proven) ----
  half8 wA[16], wLo[16];     // h-part (K blocks 0..15)
  half8 xA[2],  xLo[2];      // x-part (encoder only)

  auto stage_whh_regs = [&](const float* Whh) {
    const float* base = Whh + (size_t)growA * H + cc * 8;
#pragma unroll
    for (int kb = 0; kb < 16; ++kb) cvt8(base + kb * 32, wA[kb], wLo[kb]);
  };

  // x staging: thread (bl, sg) covers float4 chunk sg of row bl (IN=64)
  auto load_x_regs = [&](int tn, float4& p) {
    p = *(const float4*)(input + ((size_t)(bg0 + bl) * T + tn) * IN + sg * 4);
  };
  auto stage_x_regs = [&](float4 p) {
    float f[4] = {p.x, p.y, p.z, p.w};
    short4v hi, lo;
#pragma unroll
    for (int j = 0; j < 4; ++j) {
      _Float16 h_ = (_Float16)f[j];
      hi[j] = __builtin_bit_cast(short, h_);
      lo[j] = __builtin_bit_cast(short, (_Float16)(f[j] - (float)h_));
    }
    const int s2 = (NSLOT_H + (sg >> 1)) ^ (bl & 7);
    *(short4v*)&bH[bl][s2 * 8 + (sg & 1) * 4] = hi;
    *(short4v*)&bL[bl][s2 * 8 + (sg & 1) * 4] = lo;
  };

  // ---- R12-proven barrier (quorum now 32).  Release: __syncthreads (drains
  // vmcnt) + one relaxed-AGENT flag store.  Poll: lane i watches member i.
  auto gbar = [&](int nb, bool with_x, float4 xp, int gp_ot) {
    __syncthreads();
    if (tid == 0)
      __hip_atomic_store(&g_flag[gb][gj], nb, __ATOMIC_RELAXED,
                         __HIP_MEMORY_SCOPE_AGENT);
    if (with_x) stage_x_regs(xp);
    if (gp_ot >= 0 && tid < 16)   // decoder FC partial store (off crit path)
      g_part[gp_ot][gj][bg0 + tid] =
          aux[0][tid] + aux[1][tid] + aux[2][tid] + aux[3][tid];
    if (tid < 32) {
      while (__hip_atomic_load(&g_flag[gb][tid], __ATOMIC_RELAXED,
                               __HIP_MEMORY_SCOPE_AGENT) < nb)
        __builtin_amdgcn_s_sleep(1);
    }
    __syncthreads();
  };

  // h staging: dense 128B-coalesced LLC loads (16 ull/thread) + LDS commit
  auto load_h = [&](int par, ull (&tmp)[16]) {
    const ull* hr = (const ull*)&g_h[par][bg0 + bl][0];   // 256 ull per row
#pragma unroll
    for (int i = 0; i < 16; ++i)
      tmp[i] = __hip_atomic_load(hr + sg + 16 * i, __ATOMIC_RELAXED,
                                 __HIP_MEMORY_SCOPE_AGENT);
  };
  auto commit_h = [&](ull (&tmp)[16]) {
#pragma unroll
    for (int i = 0; i < 16; ++i) {
      const int m = sg + 16 * i;                 // ull index 0..255
      const int s2 = (m >> 2) ^ (bl & 7);        // swizzled 16B slot
      const int p = m & 3;                       // word within slot
      const unsigned u0 = (unsigned)tmp[i], u1 = (unsigned)(tmp[i] >> 32);
      ((unsigned*)&bH[bl][s2 * 8])[p] = (u0 >> 16) | (u1 & 0xFFFF0000u);
      ((unsigned*)&bL[bl][s2 * 8])[p] = (u0 & 0xFFFFu) | (u1 << 16);
    }
  };

  // One MFMA k-block; A from registers, B from LDS.
  auto mfma_kb = [&](int kb, half8 ah, half8 al,
                     f32x4& aA, f32x4& aB, f32x4& aC) {
    const int s2 = (kb * 4 + cc) ^ x7;
    const half8 bh = __builtin_bit_cast(half8, *(const short8*)&bH[b_l][s2 * 8]);
    const half8 bo = __builtin_bit_cast(half8, *(const short8*)&bL[b_l][s2 * 8]);
    aA = __builtin_amdgcn_mfma_f32_16x16x32_f16(ah, bh, aA, 0, 0, 0);
    aB = __builtin_amdgcn_mfma_f32_16x16x32_f16(ah, bo, aB, 0, 0, 0);
    aC = __builtin_amdgcn_mfma_f32_16x16x32_f16(al, bh, aC, 0, 0, 0);
  };

  auto wrow = [&](int r) { return (r & 3) * H + j0 + (r >> 2); };

  // ======================= one-time setup =======================
  stage_whh_regs(W_hh1);
  {  // x-part W fragments (first IN=64 cols of W_ih1)
    const float* base = W_ih1 + (size_t)growA * (IN + COV) + cc * 8;
#pragma unroll
    for (int xk = 0; xk < 2; ++xk) cvt8(base + xk * 32, xA[xk], xLo[xk]);
  }
  {  // covariate projection + b1 -> pb_lds (fp32, once): 4 rows per thread
    const float4* cv = (const float4*)(covar + (size_t)(bg0 + bt) * COV);
    float accr[4] = {0.f, 0.f, 0.f, 0.f};
    const float4* wp[4];
#pragma unroll
    for (int rr = 0; rr < 4; ++rr)
      wp[rr] = (const float4*)(W_ih1 + (size_t)wrow(rt + rr * 16) * (IN + COV) + IN);
    for (int k = 0; k < COV / 4; ++k) {
      const float4 cvk = cv[k];
#pragma unroll
      for (int rr = 0; rr < 4; ++rr) {
        const float4 w = wp[rr][k];
        accr[rr] += cvk.x * w.x + cvk.y * w.y + cvk.z * w.z + cvk.w * w.w;
      }
    }
#pragma unroll
    for (int rr = 0; rr < 4; ++rr)
      pb_lds[rt + rr * 16][bt] = accr[rr] + b1[wrow(rt + rr * 16)];
  }
  {  // stage x_0
    float4 p;
    load_x_regs(0, p);
    stage_x_regs(p);
  }
  __syncthreads();   // pb_lds + x_0 ready

  float pb4[4];
#pragma unroll
  for (int q = 0; q < 4; ++q) pb4[q] = pb_lds[rows0 + cc * 4 + q][b_l];

  float c_state = 0.0f;

  auto cellp = [&](const f32x4& acc) -> float {
    const float gi = acc[0] + pb4[0];
    const float gf = acc[1] + pb4[1];
    const float gg = acc[2] + pb4[2];
    const float go = acc[3] + pb4[3];
    c_state = sigfast(gf) * c_state + sigfast(gi) * tanhfast(gg);
    return sigfast(go) * tanhfast(c_state);
  };

  // =================== encoder: 365 steps ===================
  for (int t = 0; t < T; ++t) {
    ull tmp[16];
    if (t > 0) load_h(t & 1, tmp);             // issue 16 LLC loads
    f32x4 aA = {0.f, 0.f, 0.f, 0.f}, aB = aA, aC = aA;
#pragma unroll
    for (int xk = 0; xk < 2; ++xk)             // x part (W in regs)
      mfma_kb(16 + xk, xA[xk], xLo[xk], aA, aB, aC);
    if (t > 0) commit_h(tmp);                  // (overlapped load flight)
    __syncthreads();                           // B h-tile ready for all waves
    if (t > 0) {
#pragma unroll
      for (int kb = 0; kb < 16; ++kb)
        mfma_kb(kb, wA[kb], wLo[kb], aA, aB, aC);   // h part (W in regs)
    }
    f32x4 acc;
#pragma unroll
    for (int q = 0; q < 4; ++q) acc[q] = aA[q] + aB[q] + aC[q];
    float hv = cellp(acc);
    if (t == T - 1) hv = fmaxf(hv, 0.0f);      // relu(h_enc)
    __hip_atomic_store(&g_h[(t + 1) & 1][bg0 + b_l][j0 + u_l], pack_split(hv),
                       __ATOMIC_RELAXED, __HIP_MEMORY_SCOPE_AGENT);
    float4 xp = {0.f, 0.f, 0.f, 0.f};
    const bool havex = (t + 1 < T);
    if (havex) load_x_regs(t + 1, xp);
    gbar(t + 1, havex, xp, -1);                // stage x_{t+1} in the wait
  }

  // ====== transition: proj2 = [relu(h_enc),covar] @ W_ih2^T + b2 (fp32) ======
  {
    const ull* hb = (const ull*)&g_h[1][bg0 + bt][0];
    const float* wr[4];
    float accr[4] = {0.f, 0.f, 0.f, 0.f};
#pragma unroll
    for (int rr = 0; rr < 4; ++rr)
      wr[rr] = W_ih2 + (size_t)wrow(rt + rr * 16) * (H + COV);
    for (int m = 0; m < H / 2; ++m) {   // h part from packed LLC state
      const ull v = __hip_atomic_load(hb + m, __ATOMIC_RELAXED,
                                      __HIP_MEMORY_SCOPE_AGENT);
      const float h0 = unpack_split((unsigned)v);
      const float h1 = unpack_split((unsigned)(v >> 32));
#pragma unroll
      for (int rr = 0; rr < 4; ++rr)
        accr[rr] += h0 * wr[rr][2 * m] + h1 * wr[rr][2 * m + 1];
    }
    {  // covar part (fp32, cache-hot)
      const float4* cv = (const float4*)(covar + (size_t)(bg0 + bt) * COV);
      for (int k = 0; k < COV / 4; ++k) {
        const float4 cvk = cv[k];
#pragma unroll
        for (int rr = 0; rr < 4; ++rr) {
          const float4 w = ((const float4*)wr[rr])[H / 4 + k];
          accr[rr] += cvk.x * w.x + cvk.y * w.y + cvk.z * w.z + cvk.w * w.w;
        }
      }
    }
#pragma unroll
    for (int rr = 0; rr < 4; ++rr)
      pb_lds[rt + rr * 16][bt] = accr[rr] + b2[wrow(rt + rr * 16)];
  }
  stage_whh_regs(W_hh2);        // decoder recurrent W -> registers
  c_state = 0.0f;
  {
    float4 dummy = {0.f, 0.f, 0.f, 0.f};
    gbar(T + 1, false, dummy, -1);   // protects g_h[1] reads vs ot=0 write
  }

#pragma unroll
  for (int q = 0; q < 4; ++q) pb4[q] = pb_lds[rows0 + cc * 4 + q][b_l];
  const float wfc = W_fc[j0 + u_l];

  // =================== decoder: 90 steps ===================
  for (int ot = 0; ot < OUTL; ++ot) {
    if (ot > 0) {
      ull tmp[16];
      load_h(ot & 1, tmp);
      commit_h(tmp);
    }
    __syncthreads();
    f32x4 aA = {0.f, 0.f, 0.f, 0.f}, aB = aA, aC = aA;
    if (ot > 0) {
#pragma unroll
      for (int kb = 0; kb < 16; ++kb)
        mfma_kb(kb, wA[kb], wLo[kb], aA, aB, aC);
    }
    f32x4 acc;
#pragma unroll
    for (int q = 0; q < 4; ++q) acc[q] = aA[q] + aB[q] + aC[q];
    const float hv = cellp(acc);             // ot==0: gates = proj2 only
    __hip_atomic_store(&g_h[(ot + 1) & 1][bg0 + b_l][j0 + u_l], pack_split(hv),
                       __ATOMIC_RELAXED, __HIP_MEMORY_SCOPE_AGENT);
    // FC partial: relu(hv)*wfc; sum over cc quads then over waves via aux
    float fcv = fmaxf(hv, 0.0f) * wfc;
    fcv += __shfl_xor(fcv, 16);
    fcv += __shfl_xor(fcv, 32);              // sum over the 4 unit-lanes
    if (lane < 16) aux[wv][lane] = fcv;
    float4 dummy = {0.f, 0.f, 0.f, 0.f};
    gbar(T + 2 + ot, false, dummy, ot);      // g_part store rides the wait
  }
}

__global__ void __launch_bounds__(256) k_reduce(const float* __restrict__ b_fc,
                                                float* __restrict__ out) {
  int id = blockIdx.x * 256 + threadIdx.x;
  if (id >= B * OUTL) return;
  int b = id / OUTL, ot = id - b * OUTL;
  float s = b_fc[0];
#pragma unroll 8
  for (int g = 0; g < GJ; ++g) s += g_part[ot][g][b];
  out[id] = s;   // out[b][ot], row-major == id
}

extern "C" void kernel_launch(void* const* d_in, const int* in_sizes, int n_in,
                              void* d_out, int out_size, void* d_ws, size_t ws_size,
                              hipStream_t stream) {
  (void)in_sizes; (void)n_in; (void)d_ws; (void)ws_size; (void)out_size;
  const float* input = (const float*)d_in[0];
  const float* covar = (const float*)d_in[1];
  const float* W_ih1 = (const float*)d_in[2];
  const float* W_hh1 = (const float*)d_in[3];
  const float* b1    = (const float*)d_in[4];
  const float* W_ih2 = (const float*)d_in[5];
  const float* W_hh2 = (const float*)d_in[6];
  const float* b2    = (const float*)d_in[7];
  const float* W_fc  = (const float*)d_in[8];
  const float* b_fc  = (const float*)d_in[9];

  k_init<<<dim3(1), dim3(256), 0, stream>>>();
  k_lstm<<<dim3(NWG), dim3(NT), 0, stream>>>(input, covar, W_ih1, W_hh1, b1,
                                             W_ih2, W_hh2, b2, W_fc);
  k_reduce<<<dim3((B * OUTL + 255) / 256), dim3(256), 0, stream>>>(
      b_fc, (float*)d_out);
}